// Round 1
// baseline (2357.221 us; speedup 1.0000x reference)
//
#include <hip/hip_runtime.h>

// ---- problem constants ----
#define BATCH 2
#define DIN 65          // input spatial
#define D2IN (65*65)    // 4225
#define D3IN (65*65*65) // 274625
#define DO 32           // conv1 output spatial
#define DP 34           // padded (32 + 2 halo)
#define C2 32
#define CO 100

// workspace layout (floats)
#define H1_OFF 0
#define H1_ELEMS (2*34*34*34*32)      // 2515456
#define H2_OFF H1_ELEMS
#define M1_OFF (2*H1_ELEMS)           // 5030912
#define WT_OFF (M1_OFF + 65536)       // 5096448
// total floats: 5096448 + 86400 = 5182848  (~20.7 MB)

// ---------------- zero fill (h1pad + h2pad) ----------------
__global__ void kzero(float4* __restrict__ p, int n4) {
    int i = blockIdx.x * 256 + threadIdx.x;
    if (i < n4) p[i] = make_float4(0.f, 0.f, 0.f, 0.f);
}

// ---------------- transpose Winv[co][ci][tap] -> wt[co][tap][ci] ----------------
__global__ void ktrans(const float* __restrict__ winv, float* __restrict__ wt) {
    int o = blockIdx.x * 256 + threadIdx.x;
    if (o >= CO * 27 * 32) return;
    int ci = o & 31;
    int tmp = o >> 5;
    int tap = tmp % 27;
    int co = tmp / 27;
    wt[o] = winv[(co * 32 + ci) * 27 + tap];
}

// ---------------- K1: conv1(1->32,s2) + BN + ReLU + mask m1 ----------------
__global__ __launch_bounds__(256) void k1(
    const float* __restrict__ x, const int* __restrict__ mask0,
    const float* __restrict__ W1, const float* __restrict__ b1,
    const float* __restrict__ g1, const float* __restrict__ bt1,
    const float* __restrict__ rm1, const float* __restrict__ rv1,
    float* __restrict__ h1pad, float* __restrict__ m1)
{
    int t = blockIdx.x * 256 + threadIdx.x;   // 65536 voxels
    int b = t >> 15, r = t & 32767;
    int z = r >> 10, y = (r >> 5) & 31, xo = r & 31;

    const float* xb = x + b * D3IN;
    const int*   mb = mask0 + b * D3IN;

    float xv[27];
    int any = 0;
#pragma unroll
    for (int kd = 0; kd < 3; kd++)
#pragma unroll
        for (int kh = 0; kh < 3; kh++)
#pragma unroll
            for (int kw = 0; kw < 3; kw++) {
                int idx = (2 * z + kd) * D2IN + (2 * y + kh) * DIN + (2 * xo + kw);
                xv[kd * 9 + kh * 3 + kw] = xb[idx];
                any |= mb[idx];
            }
    float m1f = any ? 1.0f : 0.0f;
    m1[t] = m1f;

    float* out = h1pad + (((b * DP + z + 1) * DP + (y + 1)) * DP + (xo + 1)) * C2;
#pragma unroll 4
    for (int co = 0; co < 32; co++) {
        float a = 0.f;
#pragma unroll
        for (int k = 0; k < 27; k++) a += xv[k] * W1[co * 27 + k];
        float s = g1[co] * rsqrtf(rv1[co] + 1e-5f);
        float v = (a + b1[co] - rm1[co]) * s + bt1[co];
        out[co] = fmaxf(v, 0.f) * m1f;
    }
}

// ---------------- K2: conv2(32->32,k3,SAME) + BN + ReLU + mask m1 ----------------
// 256 blocks x 256 threads. Block = (co-half of 16) x (128 voxel-quads).
// Thread = 4 consecutive-x voxels x 8 output channels. W2 slice staged in LDS.
__global__ __launch_bounds__(256) void k2(
    const float* __restrict__ h1pad, const float* __restrict__ W2,
    const float* __restrict__ b2, const float* __restrict__ g2,
    const float* __restrict__ bt2, const float* __restrict__ rm2,
    const float* __restrict__ rv2, const float* __restrict__ m1,
    float* __restrict__ h2pad)
{
    __shared__ float lw[27 * 32 * 16];   // [tap][ci][co_local] , 55 KB
    int blk = blockIdx.x, tid = threadIdx.x;
    int half = blk >> 7;            // 0..1
    int cobase = half * 16;

    for (int e = tid; e < 27 * 32 * 16; e += 256) {
        int tap = e >> 9, ci = (e >> 4) & 31, col = e & 15;
        lw[e] = W2[(cobase + col) * 864 + ci * 27 + tap];
    }
    __syncthreads();

    int qidx = (blk & 127) * 128 + (tid >> 1);   // voxel quad id [0,16384)
    int cg8  = (tid & 1) * 8;                    // co_local base {0,8}
    int v0 = qidx * 4;
    int b = v0 >> 15, r = v0 & 32767;
    int z = r >> 10, y = (r >> 5) & 31, x0 = r & 31;

    float acc[4][8];
#pragma unroll
    for (int i = 0; i < 4; i++)
#pragma unroll
        for (int k = 0; k < 8; k++) acc[i][k] = 0.f;

    const float* hb = h1pad + (((b * DP + z) * DP + y) * DP + x0) * C2;

    for (int kd = 0; kd < 3; kd++)
        for (int kh = 0; kh < 3; kh++)
#pragma unroll
            for (int kw = 0; kw < 3; kw++) {
                int tap = (kd * 3 + kh) * 3 + kw;
                const float* hp = hb + ((kd * DP + kh) * DP + kw) * C2;
                const float* lwp = lw + tap * 512 + cg8;
#pragma unroll
                for (int c4 = 0; c4 < 8; c4++) {
                    float hv[4][4];
#pragma unroll
                    for (int i = 0; i < 4; i++)
                        *(float4*)hv[i] = *(const float4*)(hp + i * C2 + c4 * 4);
#pragma unroll
                    for (int j = 0; j < 4; j++) {
                        float w[8];
                        *(float4*)&w[0] = *(const float4*)(lwp + (c4 * 4 + j) * 16);
                        *(float4*)&w[4] = *(const float4*)(lwp + (c4 * 4 + j) * 16 + 4);
#pragma unroll
                        for (int i = 0; i < 4; i++)
#pragma unroll
                            for (int k = 0; k < 8; k++)
                                acc[i][k] += hv[i][j] * w[k];
                    }
                }
            }

    // epilogue: BN + ReLU + mask, store to padded h2
    float sc[8], sh[8];
#pragma unroll
    for (int j = 0; j < 8; j++) {
        int co = cobase + cg8 + j;
        float s = g2[co] * rsqrtf(rv2[co] + 1e-5f);
        sc[j] = s;
        sh[j] = (b2[co] - rm2[co]) * s + bt2[co];
    }
#pragma unroll
    for (int i = 0; i < 4; i++) {
        float mf = m1[v0 + i];
        float* op = h2pad + (((b * DP + z + 1) * DP + (y + 1)) * DP + (x0 + i + 1)) * C2
                    + cobase + cg8;
        float vals[8];
#pragma unroll
        for (int j = 0; j < 8; j++)
            vals[j] = fmaxf(acc[i][j] * sc[j] + sh[j], 0.f) * mf;
        *(float4*)op = *(float4*)&vals[0];
        *(float4*)(op + 4) = *(float4*)&vals[4];
    }
}

// ---------------- K3: inverse conv (32->100, lhs_dilation 2) + binv, masked by m0 ----------------
// Thread = (b, co, z, y, x-quad). Dense; parity-uniform tap loops; padded h2 -> no bounds checks.
#define NTH3 (2 * 100 * 65 * 65 * 17)
__global__ __launch_bounds__(256) void k3(
    const float* __restrict__ h2pad, const float* __restrict__ wt,
    const float* __restrict__ binv, const int* __restrict__ mask0,
    float* __restrict__ out)
{
    int idx = blockIdx.x * 256 + threadIdx.x;
    if (idx >= NTH3) return;
    int xq = idx % 17;  int t1 = idx / 17;
    int y  = t1 % 65;   int t2 = t1 / 65;
    int z  = t2 % 65;   int t3 = t2 / 65;
    int co = t3 % 100;  int b  = t3 / 100;
    int x0 = xq * 4;

    const int* mrow = mask0 + b * D3IN + z * D2IN + y * DIN;
    const float* wco = wt + co * 864;   // [tap][ci]

    int kd0 = z & 1, nkd = (z & 1) ? 1 : 2;
    int kh0 = y & 1, nkh = (y & 1) ? 1 : 2;

    float res[4];
#pragma unroll
    for (int xs = 0; xs < 4; xs++) {
        int xx = x0 + xs;
        float a = 0.f;
        int mv = (xx < 65) ? mrow[xx] : 0;
        if (mv) {
            a = binv[co];
            int kw0 = xx & 1, nkw = (xx & 1) ? 1 : 2;
            int kd = kd0;
            for (int ik = 0; ik < nkd; ik++, kd += 2) {
                int pz1 = ((z - 2 + kd) >> 1) + 1;          // in [0,33]
                int kh = kh0;
                for (int ih = 0; ih < nkh; ih++, kh += 2) {
                    int py1 = ((y - 2 + kh) >> 1) + 1;
                    int kw = kw0;
                    for (int iw = 0; iw < nkw; iw++, kw += 2) {
                        int px1 = ((xx - 2 + kw) >> 1) + 1;
                        const float4* h4 = (const float4*)(h2pad +
                            (((b * DP + pz1) * DP + py1) * DP + px1) * C2);
                        const float4* w4 = (const float4*)(wco + (kd * 9 + kh * 3 + kw) * 32);
#pragma unroll
                        for (int c = 0; c < 8; c++) {
                            float4 hv = h4[c], wv = w4[c];
                            a += hv.x * wv.x + hv.y * wv.y + hv.z * wv.z + hv.w * wv.w;
                        }
                    }
                }
            }
        }
        res[xs] = a;
    }

    float* orow = out + (b * 100 + co) * D3IN + z * D2IN + y * DIN + x0;
#pragma unroll
    for (int xs = 0; xs < 4; xs++)
        if (x0 + xs < 65) orow[xs] = res[xs];
}

extern "C" void kernel_launch(void* const* d_in, const int* in_sizes, int n_in,
                              void* d_out, int out_size, void* d_ws, size_t ws_size,
                              hipStream_t stream) {
    const float* x    = (const float*)d_in[0];
    const int*  mask0 = (const int*)  d_in[1];
    const float* W1   = (const float*)d_in[2];
    const float* b1   = (const float*)d_in[3];
    const float* g1   = (const float*)d_in[4];
    const float* bt1  = (const float*)d_in[5];
    const float* rm1  = (const float*)d_in[6];
    const float* rv1  = (const float*)d_in[7];
    const float* W2   = (const float*)d_in[8];
    const float* b2   = (const float*)d_in[9];
    const float* g2   = (const float*)d_in[10];
    const float* bt2  = (const float*)d_in[11];
    const float* rm2  = (const float*)d_in[12];
    const float* rv2  = (const float*)d_in[13];
    const float* Winv = (const float*)d_in[14];
    const float* binv = (const float*)d_in[15];

    float* ws   = (float*)d_ws;
    float* h1p  = ws + H1_OFF;
    float* h2p  = ws + H2_OFF;
    float* m1   = ws + M1_OFF;
    float* wt   = ws + WT_OFF;

    // zero padded h1 + h2 regions (2*2515456 floats)
    int n4 = (2 * H1_ELEMS) / 4;                       // 1257728 float4s
    kzero<<<(n4 + 255) / 256, 256, 0, stream>>>((float4*)ws, n4);

    ktrans<<<(CO * 27 * 32 + 255) / 256, 256, 0, stream>>>(Winv, wt);

    k1<<<256, 256, 0, stream>>>(x, mask0, W1, b1, g1, bt1, rm1, rv1, h1p, m1);

    k2<<<256, 256, 0, stream>>>(h1p, W2, b2, g2, bt2, rm2, rv2, m1, h2p);

    k3<<<(NTH3 + 255) / 256, 256, 0, stream>>>(h2p, wt, binv, mask0, (float*)d_out);
}

// Round 2
// 1006.261 us; speedup vs baseline: 2.3426x; 2.3426x over previous
//
#include <hip/hip_runtime.h>

// ---- problem constants ----
#define BATCH 2
#define DIN 65          // input spatial
#define D2IN (65*65)    // 4225
#define D3IN (65*65*65) // 274625
#define DO 32           // conv1 output spatial
#define DP 34           // padded (32 + 2 halo)
#define C2 32
#define CO 100
#define MAXV 65536      // max compacted active voxels (actual ~55k)

// workspace layout (float offsets)
#define H1_OFF 0
#define H1_ELEMS (2*34*34*34*32)      // 2515456
#define H2_OFF H1_ELEMS
#define M1_OFF (2*H1_ELEMS)           // 5030912
#define WT_OFF (M1_OFF + 65536)       // 5096448  (86400 floats)
#define CNT_OFF (WT_OFF + 86400)      // 5182848  (int)
#define VOX_OFF (CNT_OFF + 4)         // 5182852  (MAXV ints)
#define SIDX_OFF (VOX_OFF + MAXV)     // 5248388  (549250 ints)
#define RES_OFF 5797640               // aligned; MAXV*100 floats
// total ~12.36M floats (~49.4 MB)

// ---------------- zero fill (h1pad + h2pad) ----------------
__global__ void kzero(float4* __restrict__ p, int n4) {
    int i = blockIdx.x * 256 + threadIdx.x;
    if (i < n4) p[i] = make_float4(0.f, 0.f, 0.f, 0.f);
}

// ---------------- transpose Winv[co][ci][tap] -> wt[co][tap][ci]; zero cnt ----------------
__global__ void ktrans(const float* __restrict__ winv, float* __restrict__ wt,
                       int* __restrict__ cnt) {
    int o = blockIdx.x * 256 + threadIdx.x;
    if (o == 0) *cnt = 0;
    if (o >= CO * 27 * 32) return;
    int ci = o & 31;
    int tmp = o >> 5;
    int tap = tmp % 27;
    int co = tmp / 27;
    wt[o] = winv[(co * 32 + ci) * 27 + tap];
}

// ---------------- kA: compact active voxels of mask0 ----------------
__global__ void kcompact(const int* __restrict__ mask0, int* __restrict__ sidx,
                         int* __restrict__ vox, int* __restrict__ cnt) {
    int t = blockIdx.x * 256 + threadIdx.x;
    if (t >= 2 * D3IN) return;
    if (mask0[t]) {
        int s = atomicAdd(cnt, 1);
        if (s < MAXV) { sidx[t] = s; vox[s] = t; }
        else sidx[t] = -1;
    } else {
        sidx[t] = -1;
    }
}

// ---------------- K1: conv1(1->32,s2) + BN + ReLU + mask m1 ----------------
__global__ __launch_bounds__(256) void k1(
    const float* __restrict__ x, const int* __restrict__ mask0,
    const float* __restrict__ W1, const float* __restrict__ b1,
    const float* __restrict__ g1, const float* __restrict__ bt1,
    const float* __restrict__ rm1, const float* __restrict__ rv1,
    float* __restrict__ h1pad, float* __restrict__ m1)
{
    int t = blockIdx.x * 256 + threadIdx.x;   // 65536 voxels
    int b = t >> 15, r = t & 32767;
    int z = r >> 10, y = (r >> 5) & 31, xo = r & 31;

    const float* xb = x + b * D3IN;
    const int*   mb = mask0 + b * D3IN;

    float xv[27];
    int any = 0;
#pragma unroll
    for (int kd = 0; kd < 3; kd++)
#pragma unroll
        for (int kh = 0; kh < 3; kh++)
#pragma unroll
            for (int kw = 0; kw < 3; kw++) {
                int idx = (2 * z + kd) * D2IN + (2 * y + kh) * DIN + (2 * xo + kw);
                xv[kd * 9 + kh * 3 + kw] = xb[idx];
                any |= mb[idx];
            }
    float m1f = any ? 1.0f : 0.0f;
    m1[t] = m1f;

    float* out = h1pad + (((b * DP + z + 1) * DP + (y + 1)) * DP + (xo + 1)) * C2;
#pragma unroll 4
    for (int co = 0; co < 32; co++) {
        float a = 0.f;
#pragma unroll
        for (int k = 0; k < 27; k++) a += xv[k] * W1[co * 27 + k];
        float s = g1[co] * rsqrtf(rv1[co] + 1e-5f);
        float v = (a + b1[co] - rm1[co]) * s + bt1[co];
        out[co] = fmaxf(v, 0.f) * m1f;
    }
}

// ---------------- K2: conv2(32->32,k3,SAME) + BN + ReLU + mask m1 ----------------
__global__ __launch_bounds__(256) void k2(
    const float* __restrict__ h1pad, const float* __restrict__ W2,
    const float* __restrict__ b2, const float* __restrict__ g2,
    const float* __restrict__ bt2, const float* __restrict__ rm2,
    const float* __restrict__ rv2, const float* __restrict__ m1,
    float* __restrict__ h2pad)
{
    __shared__ float lw[27 * 32 * 16];   // [tap][ci][co_local] , 55 KB
    int blk = blockIdx.x, tid = threadIdx.x;
    int half = blk >> 7;            // 0..1
    int cobase = half * 16;

    for (int e = tid; e < 27 * 32 * 16; e += 256) {
        int tap = e >> 9, ci = (e >> 4) & 31, col = e & 15;
        lw[e] = W2[(cobase + col) * 864 + ci * 27 + tap];
    }
    __syncthreads();

    int qidx = (blk & 127) * 128 + (tid >> 1);   // voxel quad id [0,16384)
    int cg8  = (tid & 1) * 8;                    // co_local base {0,8}
    int v0 = qidx * 4;
    int b = v0 >> 15, r = v0 & 32767;
    int z = r >> 10, y = (r >> 5) & 31, x0 = r & 31;

    float acc[4][8];
#pragma unroll
    for (int i = 0; i < 4; i++)
#pragma unroll
        for (int k = 0; k < 8; k++) acc[i][k] = 0.f;

    const float* hb = h1pad + (((b * DP + z) * DP + y) * DP + x0) * C2;

    for (int kd = 0; kd < 3; kd++)
        for (int kh = 0; kh < 3; kh++)
#pragma unroll
            for (int kw = 0; kw < 3; kw++) {
                int tap = (kd * 3 + kh) * 3 + kw;
                const float* hp = hb + ((kd * DP + kh) * DP + kw) * C2;
                const float* lwp = lw + tap * 512 + cg8;
#pragma unroll
                for (int c4 = 0; c4 < 8; c4++) {
                    float hv[4][4];
#pragma unroll
                    for (int i = 0; i < 4; i++)
                        *(float4*)hv[i] = *(const float4*)(hp + i * C2 + c4 * 4);
#pragma unroll
                    for (int j = 0; j < 4; j++) {
                        float w[8];
                        *(float4*)&w[0] = *(const float4*)(lwp + (c4 * 4 + j) * 16);
                        *(float4*)&w[4] = *(const float4*)(lwp + (c4 * 4 + j) * 16 + 4);
#pragma unroll
                        for (int i = 0; i < 4; i++)
#pragma unroll
                            for (int k = 0; k < 8; k++)
                                acc[i][k] += hv[i][j] * w[k];
                    }
                }
            }

    // epilogue: BN + ReLU + mask, store to padded h2
    float sc[8], sh[8];
#pragma unroll
    for (int j = 0; j < 8; j++) {
        int co = cobase + cg8 + j;
        float s = g2[co] * rsqrtf(rv2[co] + 1e-5f);
        sc[j] = s;
        sh[j] = (b2[co] - rm2[co]) * s + bt2[co];
    }
#pragma unroll
    for (int i = 0; i < 4; i++) {
        float mf = m1[v0 + i];
        float* op = h2pad + (((b * DP + z + 1) * DP + (y + 1)) * DP + (x0 + i + 1)) * C2
                    + cobase + cg8;
        float vals[8];
#pragma unroll
        for (int j = 0; j < 8; j++)
            vals[j] = fmaxf(acc[i][j] * sc[j] + sh[j], 0.f) * mf;
        *(float4*)op = *(float4*)&vals[0];
        *(float4*)(op + 4) = *(float4*)&vals[4];
    }
}

// ---------------- kB: inverse conv compute at active voxels only ----------------
// One 128-thread block per active voxel (grid-stride). Lane = co. h2 taps in LDS.
__global__ __launch_bounds__(128) void k3compute(
    const float* __restrict__ h2pad, const float* __restrict__ wt,
    const float* __restrict__ binv, const int* __restrict__ vox,
    const int* __restrict__ cnt, float* __restrict__ res)
{
    __shared__ float lh[8 * 32];   // up to 8 taps x 32 ci
    int n = *cnt; if (n > MAXV) n = MAXV;
    int tid = threadIdx.x;

    for (int s = blockIdx.x; s < n; s += gridDim.x) {
        int v = vox[s];
        int b = v / D3IN; int r = v % D3IN;
        int z = r / D2IN; r %= D2IN;
        int y = r / DIN;  int xx = r % DIN;
        int pd = z & 1, ph = y & 1, pw = xx & 1;
        int nh = 2 - ph, nw = 2 - pw;
        int ntap = (2 - pd) * nh * nw;

        // stage h2 taps into LDS: thread (t4, c4) loads float4
        int t4 = tid >> 3, c4 = tid & 7;
        if (t4 < ntap) {
            int td = t4 / (nh * nw), rem = t4 % (nh * nw);
            int th = rem / nw, tw = rem % nw;
            int kd = pd + 2 * td, kh = ph + 2 * th, kw = pw + 2 * tw;
            int pz1 = ((z - 2 + kd) >> 1) + 1;
            int py1 = ((y - 2 + kh) >> 1) + 1;
            int px1 = ((xx - 2 + kw) >> 1) + 1;
            *(float4*)&lh[t4 * 32 + c4 * 4] =
                *(const float4*)(h2pad + (((b * DP + pz1) * DP + py1) * DP + px1) * C2 + c4 * 4);
        }
        __syncthreads();

        int co = tid;
        if (co < CO) {
            float a = binv[co];
            const float* wb = wt + co * 864;
            for (int t = 0; t < ntap; t++) {
                int td = t / (nh * nw), rem = t % (nh * nw);
                int th = rem / nw, tw = rem % nw;
                int tap = (pd + 2 * td) * 9 + (ph + 2 * th) * 3 + (pw + 2 * tw);
                const float4* w4 = (const float4*)(wb + tap * 32);
                const float4* h4 = (const float4*)&lh[t * 32];
#pragma unroll
                for (int c = 0; c < 8; c++) {
                    float4 w = w4[c], h = h4[c];
                    a += w.x * h.x + w.y * h.y + w.z * h.z + w.w * h.w;
                }
            }
            res[s * CO + co] = a;
        }
        __syncthreads();
    }
}

// ---------------- kC: dense writer — fuses zero-fill with scatter ----------------
#define NTH3 (2 * 100 * 65 * 65 * 17)
__global__ __launch_bounds__(256) void k3write(
    const float* __restrict__ res, const int* __restrict__ sidx,
    const int* __restrict__ mask0, float* __restrict__ out)
{
    int idx = blockIdx.x * 256 + threadIdx.x;
    if (idx >= NTH3) return;
    int xq = idx % 17;  int t1 = idx / 17;
    int y  = t1 % 65;   int t2 = t1 / 65;
    int z  = t2 % 65;   int t3 = t2 / 65;
    int co = t3 % 100;  int b  = t3 / 100;
    int x0 = xq * 4;

    int roff = b * D3IN + z * D2IN + y * DIN;
    const int* mrow = mask0 + roff;
    const int* srow = sidx + roff;
    float* orow = out + (b * CO + co) * D3IN + z * D2IN + y * DIN + x0;

#pragma unroll
    for (int xs = 0; xs < 4; xs++) {
        int xx = x0 + xs;
        if (xx < DIN) {
            int mv = mrow[xx];
            int s  = srow[xx];
            orow[xs] = (mv && s >= 0) ? res[s * CO + co] : 0.f;
        }
    }
}

extern "C" void kernel_launch(void* const* d_in, const int* in_sizes, int n_in,
                              void* d_out, int out_size, void* d_ws, size_t ws_size,
                              hipStream_t stream) {
    const float* x    = (const float*)d_in[0];
    const int*  mask0 = (const int*)  d_in[1];
    const float* W1   = (const float*)d_in[2];
    const float* b1   = (const float*)d_in[3];
    const float* g1   = (const float*)d_in[4];
    const float* bt1  = (const float*)d_in[5];
    const float* rm1  = (const float*)d_in[6];
    const float* rv1  = (const float*)d_in[7];
    const float* W2   = (const float*)d_in[8];
    const float* b2   = (const float*)d_in[9];
    const float* g2   = (const float*)d_in[10];
    const float* bt2  = (const float*)d_in[11];
    const float* rm2  = (const float*)d_in[12];
    const float* rv2  = (const float*)d_in[13];
    const float* Winv = (const float*)d_in[14];
    const float* binv = (const float*)d_in[15];

    float* ws   = (float*)d_ws;
    float* h1p  = ws + H1_OFF;
    float* h2p  = ws + H2_OFF;
    float* m1   = ws + M1_OFF;
    float* wt   = ws + WT_OFF;
    int*   cnt  = (int*)(ws + CNT_OFF);
    int*   vox  = (int*)(ws + VOX_OFF);
    int*   sidx = (int*)(ws + SIDX_OFF);
    float* res  = ws + RES_OFF;

    // zero padded h1 + h2 regions
    int n4 = (2 * H1_ELEMS) / 4;
    kzero<<<(n4 + 255) / 256, 256, 0, stream>>>((float4*)ws, n4);

    ktrans<<<(CO * 27 * 32 + 255) / 256, 256, 0, stream>>>(Winv, wt, cnt);

    kcompact<<<(2 * D3IN + 255) / 256, 256, 0, stream>>>(mask0, sidx, vox, cnt);

    k1<<<256, 256, 0, stream>>>(x, mask0, W1, b1, g1, bt1, rm1, rv1, h1p, m1);

    k2<<<256, 256, 0, stream>>>(h1p, W2, b2, g2, bt2, rm2, rv2, m1, h2p);

    k3compute<<<8192, 128, 0, stream>>>(h2p, wt, binv, vox, cnt, res);

    k3write<<<(NTH3 + 255) / 256, 256, 0, stream>>>(res, sidx, mask0, (float*)d_out);
}

// Round 3
// 696.702 us; speedup vs baseline: 3.3834x; 1.4443x over previous
//
#include <hip/hip_runtime.h>

// ---- problem constants ----
#define BATCH 2
#define DIN 65          // input spatial
#define D2IN (65*65)    // 4225
#define D3IN (65*65*65) // 274625
#define DO 32           // conv1 output spatial
#define DP 34           // padded (32 + 2 halo)
#define C2 32
#define CO 100
#define CAP 8192        // per parity-class slot capacity (8*8192 = 65536)
#define NB3 64          // k3compute grid.x

// workspace layout (float offsets)
#define H1_OFF 0
#define H1_ELEMS (2*34*34*34*32)        // 2515456
#define H2_OFF H1_ELEMS
#define M1_OFF (2*H1_ELEMS)             // 5030912 (65536)
#define WT2_OFF (M1_OFF + 65536)        // 5096448 (27*32*100 = 86400)
#define CNT8_OFF (WT2_OFF + 86400)      // 5182848 (8 ints)
#define VOX_OFF (CNT8_OFF + 8)          // 5182856 (65536 ints)
#define SIDX_OFF (VOX_OFF + 65536)      // 5248392 (549250 ints)
#define RES_OFF 5797648                 // 16B aligned; 65536*100 floats
// total = 12351248 floats ~= 49.4 MB

// ---------------- zero fill (h1pad + h2pad) ----------------
__global__ void kzero(float4* __restrict__ p, int n4) {
    int i = blockIdx.x * 256 + threadIdx.x;
    if (i < n4) p[i] = make_float4(0.f, 0.f, 0.f, 0.f);
}

// ---------------- wt2[tap][ci][co] <- Winv[co][ci][tap]; zero cnt8 ----------------
__global__ void ktrans(const float* __restrict__ winv, float* __restrict__ wt2,
                       int* __restrict__ cnt8) {
    int o = blockIdx.x * 256 + threadIdx.x;
    if (o < 8) cnt8[o] = 0;
    if (o >= 27 * 32 * 100) return;
    int co = o % 100; int t = o / 100;
    int ci = t & 31;  int tap = t >> 5;
    wt2[o] = winv[(co * 32 + ci) * 27 + tap];
}

// ---------------- kcompact: bucket active voxels by parity class ----------------
__global__ __launch_bounds__(256) void kcompact(
    const int* __restrict__ mask0, int* __restrict__ sidx,
    int* __restrict__ vox, int* __restrict__ cnt8)
{
    __shared__ int lcnt[8];
    __shared__ int lbase[8];
    int tid = threadIdx.x;
    int t = blockIdx.x * 256 + tid;
    if (tid < 8) lcnt[tid] = 0;
    __syncthreads();
    int valid = (t < 2 * D3IN);
    int m = valid ? mask0[t] : 0;
    int cls = 0, loff = 0;
    if (m) {
        int r = t % D3IN;
        int z = r / D2IN; int rem = r % D2IN;
        int y = rem / DIN; int x = rem % DIN;
        cls = ((z & 1) << 2) | ((y & 1) << 1) | (x & 1);
        loff = atomicAdd(&lcnt[cls], 1);
    }
    __syncthreads();
    if (tid < 8)
        lbase[tid] = lcnt[tid] ? atomicAdd(&cnt8[tid], lcnt[tid]) : 0;
    __syncthreads();
    if (valid) {
        if (m) {
            int slot = lbase[cls] + loff;
            if (slot < CAP) {
                int g = cls * CAP + slot;
                sidx[t] = g;
                vox[g] = t;
            } else sidx[t] = -1;
        } else sidx[t] = -1;
    }
}

// ---------------- K1: conv1(1->32,s2) + BN + ReLU + mask m1 ----------------
__global__ __launch_bounds__(256) void k1(
    const float* __restrict__ x, const int* __restrict__ mask0,
    const float* __restrict__ W1, const float* __restrict__ b1,
    const float* __restrict__ g1, const float* __restrict__ bt1,
    const float* __restrict__ rm1, const float* __restrict__ rv1,
    float* __restrict__ h1pad, float* __restrict__ m1)
{
    int t = blockIdx.x * 256 + threadIdx.x;   // 65536 voxels
    int b = t >> 15, r = t & 32767;
    int z = r >> 10, y = (r >> 5) & 31, xo = r & 31;

    const float* xb = x + b * D3IN;
    const int*   mb = mask0 + b * D3IN;

    float xv[27];
    int any = 0;
#pragma unroll
    for (int kd = 0; kd < 3; kd++)
#pragma unroll
        for (int kh = 0; kh < 3; kh++)
#pragma unroll
            for (int kw = 0; kw < 3; kw++) {
                int idx = (2 * z + kd) * D2IN + (2 * y + kh) * DIN + (2 * xo + kw);
                xv[kd * 9 + kh * 3 + kw] = xb[idx];
                any |= mb[idx];
            }
    float m1f = any ? 1.0f : 0.0f;
    m1[t] = m1f;

    float* out = h1pad + (((b * DP + z + 1) * DP + (y + 1)) * DP + (xo + 1)) * C2;
#pragma unroll 4
    for (int co = 0; co < 32; co++) {
        float a = 0.f;
#pragma unroll
        for (int k = 0; k < 27; k++) a += xv[k] * W1[co * 27 + k];
        float s = g1[co] * rsqrtf(rv1[co] + 1e-5f);
        float v = (a + b1[co] - rm1[co]) * s + bt1[co];
        out[co] = fmaxf(v, 0.f) * m1f;
    }
}

// ---------------- K2: conv2(32->32,k3,SAME) + BN + ReLU + mask m1 ----------------
// 512 blocks x 256 threads (2 blocks/CU, 8 waves/CU). Thread = 2 voxels x 8 cos.
__global__ __launch_bounds__(256) void k2(
    const float* __restrict__ h1pad, const float* __restrict__ W2,
    const float* __restrict__ b2, const float* __restrict__ g2,
    const float* __restrict__ bt2, const float* __restrict__ rm2,
    const float* __restrict__ rv2, const float* __restrict__ m1,
    float* __restrict__ h2pad)
{
    __shared__ float lw[27 * 32 * 16];   // [tap][ci][co_local], 55 KB
    int blk = blockIdx.x, tid = threadIdx.x;
    int half = blk >> 8;            // 0..1
    int cobase = half * 16;

    for (int e = tid; e < 27 * 32 * 16; e += 256) {
        int tap = e >> 9, ci = (e >> 4) & 31, col = e & 15;
        lw[e] = W2[(cobase + col) * 864 + ci * 27 + tap];
    }
    __syncthreads();

    int p = (blk & 255) * 128 + (tid >> 1);   // voxel pair id [0,32768)
    int cg8 = (tid & 1) * 8;
    int v0 = p * 2;
    int b = v0 >> 15, r = v0 & 32767;
    int z = r >> 10, y = (r >> 5) & 31, x0 = r & 31;

    float acc[2][8];
#pragma unroll
    for (int i = 0; i < 2; i++)
#pragma unroll
        for (int k = 0; k < 8; k++) acc[i][k] = 0.f;

    const float* hb = h1pad + (((b * DP + z) * DP + y) * DP + x0) * C2;

    for (int kd = 0; kd < 3; kd++)
        for (int kh = 0; kh < 3; kh++)
#pragma unroll
            for (int kw = 0; kw < 3; kw++) {
                int tap = (kd * 3 + kh) * 3 + kw;
                const float* hp = hb + ((kd * DP + kh) * DP + kw) * C2;
                const float* lwp = lw + tap * 512 + cg8;
#pragma unroll
                for (int c4 = 0; c4 < 8; c4++) {
                    float hv[2][4];
#pragma unroll
                    for (int i = 0; i < 2; i++)
                        *(float4*)hv[i] = *(const float4*)(hp + i * C2 + c4 * 4);
#pragma unroll
                    for (int j = 0; j < 4; j++) {
                        float w[8];
                        *(float4*)&w[0] = *(const float4*)(lwp + (c4 * 4 + j) * 16);
                        *(float4*)&w[4] = *(const float4*)(lwp + (c4 * 4 + j) * 16 + 4);
#pragma unroll
                        for (int i = 0; i < 2; i++)
#pragma unroll
                            for (int k = 0; k < 8; k++)
                                acc[i][k] += hv[i][j] * w[k];
                    }
                }
            }

    float sc[8], sh[8];
#pragma unroll
    for (int j = 0; j < 8; j++) {
        int co = cobase + cg8 + j;
        float s = g2[co] * rsqrtf(rv2[co] + 1e-5f);
        sc[j] = s;
        sh[j] = (b2[co] - rm2[co]) * s + bt2[co];
    }
#pragma unroll
    for (int i = 0; i < 2; i++) {
        float mf = m1[v0 + i];
        float* op = h2pad + (((b * DP + z + 1) * DP + (y + 1)) * DP + (x0 + i + 1)) * C2
                    + cobase + cg8;
        float vals[8];
#pragma unroll
        for (int j = 0; j < 8; j++)
            vals[j] = fmaxf(acc[i][j] * sc[j] + sh[j], 0.f) * mf;
        *(float4*)op = *(float4*)&vals[0];
        *(float4*)(op + 4) = *(float4*)&vals[4];
    }
}

// ---------------- k3compute v2: parity-class, weights in LDS, wave = voxel-quad ----------------
// grid (NB3, 8 classes, 2 co-halves) x 256. Block stages class weights [tap][ci][co50 pad52].
__global__ __launch_bounds__(256) void k3compute(
    const float* __restrict__ h2pad, const float* __restrict__ wt2,
    const float* __restrict__ binv, const int* __restrict__ vox,
    const int* __restrict__ cnt8, float* __restrict__ res)
{
    __shared__ float lw[8 * 32 * 52 + 32];
    int cls = blockIdx.y;
    int half = blockIdx.z;
    int pd = (cls >> 2) & 1, ph = (cls >> 1) & 1, pw = cls & 1;
    int nh = 2 - ph, nw = 2 - pw;
    int ntap = (2 - pd) * nh * nw;
    int tid = threadIdx.x;

    // stage weights
    int nelem = ntap * 32 * 50;
    for (int e = tid; e < nelem; e += 256) {
        int co = e % 50; int t = e / 50;
        int ci = t & 31;  int tl = t >> 5;
        int td = tl / (nh * nw); int rr = tl % (nh * nw);
        int th = rr / nw; int tw = rr % nw;
        int tap = (pd + 2 * td) * 9 + (ph + 2 * th) * 3 + (pw + 2 * tw);
        lw[t * 52 + co] = wt2[(tap * 32 + ci) * 100 + half * 50 + co];
    }
    __syncthreads();

    int wv = tid >> 6, lane = tid & 63;
    int co = half * 50 + ((lane < 50) ? lane : 49);
    float bv = binv[co];
    int n = cnt8[cls]; if (n > CAP) n = CAP;

    for (int q = blockIdx.x * 4 + wv; q * 4 < n; q += NB3 * 4) {
        // decode 4 voxels (clamp tail to first voxel of quad; guard at write)
        int vb[4], vz[4], vy[4], vxx[4];
#pragma unroll
        for (int v = 0; v < 4; v++) {
            int idx = q * 4 + v;
            if (idx >= n) idx = q * 4;
            int vx = vox[cls * CAP + idx];
            int b = vx / D3IN; int r = vx % D3IN;
            int z = r / D2IN; int rem = r % D2IN;
            int y = rem / DIN; int xx = rem % DIN;
            vb[v] = b; vz[v] = (z >> 1) + pd; vy[v] = (y >> 1) + ph; vxx[v] = (xx >> 1) + pw;
        }
        float acc[4] = {0.f, 0.f, 0.f, 0.f};

        for (int tl = 0; tl < ntap; tl++) {
            int td = tl / (nh * nw); int rr = tl % (nh * nw);
            int th = rr / nw; int tw = rr % nw;
            const float* hp[4];
#pragma unroll
            for (int v = 0; v < 4; v++)
                hp[v] = h2pad + (((vb[v] * DP + vz[v] + td) * DP + vy[v] + th) * DP
                                 + vxx[v] + tw) * C2;
#pragma unroll
            for (int ch = 0; ch < 4; ch++) {
                float4 ha[4], hb4[4];
#pragma unroll
                for (int v = 0; v < 4; v++) {
                    ha[v]  = *(const float4*)(hp[v] + ch * 8);
                    hb4[v] = *(const float4*)(hp[v] + ch * 8 + 4);
                }
                float w[8];
#pragma unroll
                for (int j = 0; j < 8; j++)
                    w[j] = lw[(tl * 32 + ch * 8 + j) * 52 + lane];
#pragma unroll
                for (int v = 0; v < 4; v++) {
                    acc[v] += ha[v].x * w[0] + ha[v].y * w[1]
                            + ha[v].z * w[2] + ha[v].w * w[3]
                            + hb4[v].x * w[4] + hb4[v].y * w[5]
                            + hb4[v].z * w[6] + hb4[v].w * w[7];
                }
            }
        }
        if (lane < 50) {
#pragma unroll
            for (int v = 0; v < 4; v++)
                if (q * 4 + v < n)
                    res[(cls * CAP + q * 4 + v) * 100 + co] = acc[v] + bv;
        }
    }
}

// ---------------- k3write: dense coalesced writer (fuses zero-fill + scatter) ----------------
#define NTH3 (2 * 100 * 65 * 65 * 17)
__global__ __launch_bounds__(256) void k3write(
    const float* __restrict__ res, const int* __restrict__ sidx,
    float* __restrict__ out)
{
    int idx = blockIdx.x * 256 + threadIdx.x;
    if (idx >= NTH3) return;
    int xq = idx % 17;  int t1 = idx / 17;
    int y  = t1 % 65;   int t2 = t1 / 65;
    int z  = t2 % 65;   int t3 = t2 / 65;
    int co = t3 % 100;  int b  = t3 / 100;
    int x0 = xq * 4;

    int roff = b * D3IN + z * D2IN + y * DIN;
    const int* srow = sidx + roff;
    float* orow = out + (b * CO + co) * D3IN + z * D2IN + y * DIN + x0;

#pragma unroll
    for (int xs = 0; xs < 4; xs++) {
        int xx = x0 + xs;
        if (xx < DIN) {
            int s = srow[xx];
            orow[xs] = (s >= 0) ? res[s * CO + co] : 0.f;
        }
    }
}

extern "C" void kernel_launch(void* const* d_in, const int* in_sizes, int n_in,
                              void* d_out, int out_size, void* d_ws, size_t ws_size,
                              hipStream_t stream) {
    const float* x    = (const float*)d_in[0];
    const int*  mask0 = (const int*)  d_in[1];
    const float* W1   = (const float*)d_in[2];
    const float* b1   = (const float*)d_in[3];
    const float* g1   = (const float*)d_in[4];
    const float* bt1  = (const float*)d_in[5];
    const float* rm1  = (const float*)d_in[6];
    const float* rv1  = (const float*)d_in[7];
    const float* W2   = (const float*)d_in[8];
    const float* b2   = (const float*)d_in[9];
    const float* g2   = (const float*)d_in[10];
    const float* bt2  = (const float*)d_in[11];
    const float* rm2  = (const float*)d_in[12];
    const float* rv2  = (const float*)d_in[13];
    const float* Winv = (const float*)d_in[14];
    const float* binv = (const float*)d_in[15];

    float* ws   = (float*)d_ws;
    float* h1p  = ws + H1_OFF;
    float* h2p  = ws + H2_OFF;
    float* m1   = ws + M1_OFF;
    float* wt2  = ws + WT2_OFF;
    int*   cnt8 = (int*)(ws + CNT8_OFF);
    int*   vox  = (int*)(ws + VOX_OFF);
    int*   sidx = (int*)(ws + SIDX_OFF);
    float* res  = ws + RES_OFF;

    int n4 = (2 * H1_ELEMS) / 4;
    kzero<<<(n4 + 255) / 256, 256, 0, stream>>>((float4*)ws, n4);

    ktrans<<<(27 * 32 * 100 + 255) / 256, 256, 0, stream>>>(Winv, wt2, cnt8);

    kcompact<<<(2 * D3IN + 255) / 256, 256, 0, stream>>>(mask0, sidx, vox, cnt8);

    k1<<<256, 256, 0, stream>>>(x, mask0, W1, b1, g1, bt1, rm1, rv1, h1p, m1);

    k2<<<512, 256, 0, stream>>>(h1p, W2, b2, g2, bt2, rm2, rv2, m1, h2p);

    k3compute<<<dim3(NB3, 8, 2), 256, 0, stream>>>(h2p, wt2, binv, vox, cnt8, res);

    k3write<<<(NTH3 + 255) / 256, 256, 0, stream>>>(res, sidx, (float*)d_out);
}

// Round 4
// 669.799 us; speedup vs baseline: 3.5193x; 1.0402x over previous
//
#include <hip/hip_runtime.h>

// ---- problem constants ----
#define BATCH 2
#define DIN 65          // input spatial
#define D2IN (65*65)    // 4225
#define D3IN (65*65*65) // 274625
#define NTOT (2*D3IN)   // 549250
#define DO 32           // conv1 output spatial
#define DP 34           // padded (32 + 2 halo)
#define C2 32
#define CO 100
#define CAP 8192        // per parity-class slot capacity (8*8192 = 65536)
#define NB3 64          // k3compute grid.x

// workspace layout (float offsets)
#define H1_OFF 0
#define H1_ELEMS (2*34*34*34*32)        // 2515456
#define H2_OFF H1_ELEMS
#define M1_OFF (2*H1_ELEMS)             // 5030912 (65536)
#define WT2_OFF (M1_OFF + 65536)        // 5096448 (27*32*100 = 86400)
#define CNT8_OFF (WT2_OFF + 86400)      // 5182848 (8 ints)
#define VOX_OFF (CNT8_OFF + 8)          // 5182856 (65536 ints)
#define SIDX_OFF (VOX_OFF + 65536)      // 5248392 (549250 ints)
#define RES_OFF 5797648                 // 16B aligned; 65536*100 floats
// total = 12351248 floats ~= 49.4 MB

// ---------------- kprep: zero h1pad+h2pad, transpose Winv, zero cnt8 ----------------
__global__ __launch_bounds__(256) void kprep(
    float4* __restrict__ zp, int n4,
    const float* __restrict__ winv, float* __restrict__ wt2, int* __restrict__ cnt8)
{
    int gid = blockIdx.x * 256 + threadIdx.x;
    int stride = gridDim.x * 256;
    for (int i = gid; i < n4; i += stride) zp[i] = make_float4(0.f, 0.f, 0.f, 0.f);
    for (int o = gid; o < 27 * 32 * 100; o += stride) {
        int co = o % 100; int t = o / 100;
        int ci = t & 31;  int tap = t >> 5;
        wt2[o] = winv[(co * 32 + ci) * 27 + tap];
    }
    if (gid < 8) cnt8[gid] = 0;
}

// ---------------- kcompact v3: two-sweep block-aggregated bucketing ----------------
// 256 blocks; 8 global atomics per block. Emits packed coords (b<<21|z<<14|y<<7|x).
__global__ __launch_bounds__(256) void kcompact(
    const int* __restrict__ mask0, int* __restrict__ sidx,
    int* __restrict__ vox, int* __restrict__ cnt8)
{
    __shared__ int lcnt[8], lbase[8];
    int tid = threadIdx.x;
    const int chunk = (NTOT + 255) / 256;   // per-block element count (gridDim.x==256)
    int start = blockIdx.x * chunk;
    int end = start + chunk; if (end > NTOT) end = NTOT;
    if (tid < 8) lcnt[tid] = 0;
    __syncthreads();
    for (int t = start + tid; t < end; t += 256) {
        if (mask0[t]) {
            int r = t % D3IN;
            int z = r / D2IN; int rem = r % D2IN;
            int y = rem / DIN; int x = rem % DIN;
            atomicAdd(&lcnt[((z & 1) << 2) | ((y & 1) << 1) | (x & 1)], 1);
        }
    }
    __syncthreads();
    if (tid < 8) {
        lbase[tid] = lcnt[tid] ? atomicAdd(&cnt8[tid], lcnt[tid]) : 0;
        lcnt[tid] = 0;
    }
    __syncthreads();
    for (int t = start + tid; t < end; t += 256) {
        int s = -1;
        if (mask0[t]) {
            int bb = t / D3IN; int r = t % D3IN;
            int z = r / D2IN; int rem = r % D2IN;
            int y = rem / DIN; int x = rem % DIN;
            int cls = ((z & 1) << 2) | ((y & 1) << 1) | (x & 1);
            int loff = atomicAdd(&lcnt[cls], 1);
            int slot = lbase[cls] + loff;
            if (slot < CAP) {
                s = cls * CAP + slot;
                vox[s] = (bb << 21) | (z << 14) | (y << 7) | x;
            }
        }
        sidx[t] = s;
    }
}

// ---------------- K1: conv1(1->32,s2) + BN + ReLU + mask m1 (float4 stores) ----------------
__global__ __launch_bounds__(128) void k1(
    const float* __restrict__ x, const int* __restrict__ mask0,
    const float* __restrict__ W1, const float* __restrict__ b1,
    const float* __restrict__ g1, const float* __restrict__ bt1,
    const float* __restrict__ rm1, const float* __restrict__ rv1,
    float* __restrict__ h1pad, float* __restrict__ m1)
{
    int t = blockIdx.x * 128 + threadIdx.x;   // 65536 voxels
    int b = t >> 15, r = t & 32767;
    int z = r >> 10, y = (r >> 5) & 31, xo = r & 31;

    const float* xb = x + b * D3IN;
    const int*   mb = mask0 + b * D3IN;

    float xv[27];
    int any = 0;
#pragma unroll
    for (int kd = 0; kd < 3; kd++)
#pragma unroll
        for (int kh = 0; kh < 3; kh++)
#pragma unroll
            for (int kw = 0; kw < 3; kw++) {
                int idx = (2 * z + kd) * D2IN + (2 * y + kh) * DIN + (2 * xo + kw);
                xv[kd * 9 + kh * 3 + kw] = xb[idx];
                any |= mb[idx];
            }
    float m1f = any ? 1.0f : 0.0f;
    m1[t] = m1f;

    float vals[32];
#pragma unroll 4
    for (int co = 0; co < 32; co++) {
        float a = 0.f;
#pragma unroll
        for (int k = 0; k < 27; k++) a += xv[k] * W1[co * 27 + k];
        float s = g1[co] * rsqrtf(rv1[co] + 1e-5f);
        float v = (a + b1[co] - rm1[co]) * s + bt1[co];
        vals[co] = fmaxf(v, 0.f) * m1f;
    }
    float4* out4 = (float4*)(h1pad + (((b * DP + z + 1) * DP + (y + 1)) * DP + (xo + 1)) * C2);
#pragma unroll
    for (int q = 0; q < 8; q++) out4[q] = *(float4*)&vals[q * 4];
}

// ---------------- K2: conv2(32->32,k3,SAME) + BN + ReLU + mask m1 ----------------
__global__ __launch_bounds__(256) void k2(
    const float* __restrict__ h1pad, const float* __restrict__ W2,
    const float* __restrict__ b2, const float* __restrict__ g2,
    const float* __restrict__ bt2, const float* __restrict__ rm2,
    const float* __restrict__ rv2, const float* __restrict__ m1,
    float* __restrict__ h2pad)
{
    __shared__ float lw[27 * 32 * 16];   // [tap][ci][co_local], 55 KB
    int blk = blockIdx.x, tid = threadIdx.x;
    int half = blk >> 8;            // 0..1
    int cobase = half * 16;

    for (int e = tid; e < 27 * 32 * 16; e += 256) {
        int tap = e >> 9, ci = (e >> 4) & 31, col = e & 15;
        lw[e] = W2[(cobase + col) * 864 + ci * 27 + tap];
    }
    __syncthreads();

    int p = (blk & 255) * 128 + (tid >> 1);   // voxel pair id [0,32768)
    int cg8 = (tid & 1) * 8;
    int v0 = p * 2;
    int b = v0 >> 15, r = v0 & 32767;
    int z = r >> 10, y = (r >> 5) & 31, x0 = r & 31;

    float acc[2][8];
#pragma unroll
    for (int i = 0; i < 2; i++)
#pragma unroll
        for (int k = 0; k < 8; k++) acc[i][k] = 0.f;

    const float* hb = h1pad + (((b * DP + z) * DP + y) * DP + x0) * C2;

    for (int kd = 0; kd < 3; kd++)
        for (int kh = 0; kh < 3; kh++)
#pragma unroll
            for (int kw = 0; kw < 3; kw++) {
                int tap = (kd * 3 + kh) * 3 + kw;
                const float* hp = hb + ((kd * DP + kh) * DP + kw) * C2;
                const float* lwp = lw + tap * 512 + cg8;
#pragma unroll
                for (int c4 = 0; c4 < 8; c4++) {
                    float hv[2][4];
#pragma unroll
                    for (int i = 0; i < 2; i++)
                        *(float4*)hv[i] = *(const float4*)(hp + i * C2 + c4 * 4);
#pragma unroll
                    for (int j = 0; j < 4; j++) {
                        float w[8];
                        *(float4*)&w[0] = *(const float4*)(lwp + (c4 * 4 + j) * 16);
                        *(float4*)&w[4] = *(const float4*)(lwp + (c4 * 4 + j) * 16 + 4);
#pragma unroll
                        for (int i = 0; i < 2; i++)
#pragma unroll
                            for (int k = 0; k < 8; k++)
                                acc[i][k] += hv[i][j] * w[k];
                    }
                }
            }

    float sc[8], sh[8];
#pragma unroll
    for (int j = 0; j < 8; j++) {
        int co = cobase + cg8 + j;
        float s = g2[co] * rsqrtf(rv2[co] + 1e-5f);
        sc[j] = s;
        sh[j] = (b2[co] - rm2[co]) * s + bt2[co];
    }
#pragma unroll
    for (int i = 0; i < 2; i++) {
        float mf = m1[v0 + i];
        float* op = h2pad + (((b * DP + z + 1) * DP + (y + 1)) * DP + (x0 + i + 1)) * C2
                    + cobase + cg8;
        float vals[8];
#pragma unroll
        for (int j = 0; j < 8; j++)
            vals[j] = fmaxf(acc[i][j] * sc[j] + sh[j], 0.f) * mf;
        *(float4*)op = *(float4*)&vals[0];
        *(float4*)(op + 4) = *(float4*)&vals[4];
    }
}

// ---------------- k3compute v3: bf16 weights in LDS, 8 vox/wave-iter ----------------
// grid (NB3, 8 classes, 2 co-halves) x 256. LDS = ntap*16*50 uints <= 25.6 KB.
__global__ __launch_bounds__(256) void k3compute(
    const float* __restrict__ h2pad, const float* __restrict__ wt2,
    const float* __restrict__ binv, const int* __restrict__ vox,
    const int* __restrict__ cnt8, float* __restrict__ res)
{
    __shared__ unsigned int lw[8 * 16 * 50];
    __shared__ int stoff[8];
    int cls = blockIdx.y, half = blockIdx.z;
    int pd = (cls >> 2) & 1, ph = (cls >> 1) & 1, pw = cls & 1;
    int nh = 2 - ph, nw = 2 - pw, nhw = nh * nw;
    int ntap = (2 - pd) * nhw;
    int tid = threadIdx.x;

    if (tid < ntap) {
        int td = tid / nhw, rr = tid % nhw, th = rr / nw, tw = rr % nw;
        stoff[tid] = ((td * DP + th) * DP + tw) * C2;
    }
    int nelem = ntap * 16 * 50;
    for (int e = tid; e < nelem; e += 256) {
        int co = e % 50; int t = e / 50;
        int cp = t & 15, tl = t >> 4;
        int td = tl / nhw, rr = tl % nhw, th = rr / nw, tw = rr % nw;
        int tap = (pd + 2 * td) * 9 + (ph + 2 * th) * 3 + (pw + 2 * tw);
        float w0 = wt2[(tap * 32 + 2 * cp) * 100 + half * 50 + co];
        float w1 = wt2[(tap * 32 + 2 * cp + 1) * 100 + half * 50 + co];
        unsigned int b0 = __float_as_uint(w0), b1 = __float_as_uint(w1);
        unsigned int r0 = ((b0 + 0x7fffu + ((b0 >> 16) & 1u)) >> 16) & 0xffffu;
        unsigned int r1 = (b1 + 0x7fffu + ((b1 >> 16) & 1u)) & 0xffff0000u;
        lw[t * 50 + co] = r0 | r1;
    }
    __syncthreads();

    int wv = tid >> 6, lane = tid & 63;
    int lc = (lane < 50) ? lane : 49;
    int co = half * 50 + lc;
    float bv = binv[co];
    int n = cnt8[cls]; if (n > CAP) n = CAP;

    for (int g = blockIdx.x * 4 + wv; g * 8 < n; g += NB3 * 4) {
        int base[8];
#pragma unroll
        for (int v = 0; v < 8; v++) {
            int idx = g * 8 + v; if (idx >= n) idx = n - 1;
            unsigned int pv = (unsigned int)vox[cls * CAP + idx];
            int xx = pv & 127, y = (pv >> 7) & 127, z = (pv >> 14) & 127, bb = (pv >> 21) & 1;
            base[v] = (((bb * DP + (z >> 1) + pd) * DP + (y >> 1) + ph) * DP
                       + (xx >> 1) + pw) * C2;
        }
        float acc[8] = {0.f, 0.f, 0.f, 0.f, 0.f, 0.f, 0.f, 0.f};
        for (int tl = 0; tl < ntap; tl++) {
            int toff = stoff[tl];
#pragma unroll
            for (int ch = 0; ch < 4; ch++) {
                unsigned int u0 = lw[(tl * 16 + ch * 4 + 0) * 50 + lc];
                unsigned int u1 = lw[(tl * 16 + ch * 4 + 1) * 50 + lc];
                unsigned int u2 = lw[(tl * 16 + ch * 4 + 2) * 50 + lc];
                unsigned int u3 = lw[(tl * 16 + ch * 4 + 3) * 50 + lc];
                float w0 = __uint_as_float(u0 << 16), w1 = __uint_as_float(u0 & 0xffff0000u);
                float w2 = __uint_as_float(u1 << 16), w3 = __uint_as_float(u1 & 0xffff0000u);
                float w4 = __uint_as_float(u2 << 16), w5 = __uint_as_float(u2 & 0xffff0000u);
                float w6 = __uint_as_float(u3 << 16), w7 = __uint_as_float(u3 & 0xffff0000u);
#pragma unroll
                for (int v = 0; v < 8; v++) {
                    const float* hp = h2pad + base[v] + toff + ch * 8;
                    float4 h0 = *(const float4*)hp;
                    float4 h1 = *(const float4*)(hp + 4);
                    acc[v] += h0.x * w0 + h0.y * w1 + h0.z * w2 + h0.w * w3
                            + h1.x * w4 + h1.y * w5 + h1.z * w6 + h1.w * w7;
                }
            }
        }
        if (lane < 50) {
#pragma unroll
            for (int v = 0; v < 8; v++) {
                int idx = g * 8 + v;
                if (idx < n) res[(cls * CAP + idx) * 100 + co] = acc[v] + bv;
            }
        }
    }
}

// ---------------- k3write: dense coalesced writer (fuses zero-fill + scatter) ----------------
#define NTH3 (2 * 100 * 65 * 65 * 17)
__global__ __launch_bounds__(256) void k3write(
    const float* __restrict__ res, const int* __restrict__ sidx,
    float* __restrict__ out)
{
    int idx = blockIdx.x * 256 + threadIdx.x;
    if (idx >= NTH3) return;
    int xq = idx % 17;  int t1 = idx / 17;
    int y  = t1 % 65;   int t2 = t1 / 65;
    int z  = t2 % 65;   int t3 = t2 / 65;
    int co = t3 % 100;  int b  = t3 / 100;
    int x0 = xq * 4;

    int roff = b * D3IN + z * D2IN + y * DIN;
    const int* srow = sidx + roff;
    float* orow = out + (b * CO + co) * D3IN + z * D2IN + y * DIN + x0;

    if (x0 + 3 < DIN) {
#pragma unroll
        for (int xs = 0; xs < 4; xs++) {
            int s = srow[x0 + xs];
            orow[xs] = (s >= 0) ? res[s * CO + co] : 0.f;
        }
    } else {
        int s = srow[64];
        orow[0] = (s >= 0) ? res[s * CO + co] : 0.f;
    }
}

extern "C" void kernel_launch(void* const* d_in, const int* in_sizes, int n_in,
                              void* d_out, int out_size, void* d_ws, size_t ws_size,
                              hipStream_t stream) {
    const float* x    = (const float*)d_in[0];
    const int*  mask0 = (const int*)  d_in[1];
    const float* W1   = (const float*)d_in[2];
    const float* b1   = (const float*)d_in[3];
    const float* g1   = (const float*)d_in[4];
    const float* bt1  = (const float*)d_in[5];
    const float* rm1  = (const float*)d_in[6];
    const float* rv1  = (const float*)d_in[7];
    const float* W2   = (const float*)d_in[8];
    const float* b2   = (const float*)d_in[9];
    const float* g2   = (const float*)d_in[10];
    const float* bt2  = (const float*)d_in[11];
    const float* rm2  = (const float*)d_in[12];
    const float* rv2  = (const float*)d_in[13];
    const float* Winv = (const float*)d_in[14];
    const float* binv = (const float*)d_in[15];

    float* ws   = (float*)d_ws;
    float* h1p  = ws + H1_OFF;
    float* h2p  = ws + H2_OFF;
    float* m1   = ws + M1_OFF;
    float* wt2  = ws + WT2_OFF;
    int*   cnt8 = (int*)(ws + CNT8_OFF);
    int*   vox  = (int*)(ws + VOX_OFF);
    int*   sidx = (int*)(ws + SIDX_OFF);
    float* res  = ws + RES_OFF;

    int n4 = (2 * H1_ELEMS) / 4;
    kprep<<<1024, 256, 0, stream>>>((float4*)ws, n4, Winv, wt2, cnt8);

    kcompact<<<256, 256, 0, stream>>>(mask0, sidx, vox, cnt8);

    k1<<<512, 128, 0, stream>>>(x, mask0, W1, b1, g1, bt1, rm1, rv1, h1p, m1);

    k2<<<512, 256, 0, stream>>>(h1p, W2, b2, g2, bt2, rm2, rv2, m1, h2p);

    k3compute<<<dim3(NB3, 8, 2), 256, 0, stream>>>(h2p, wt2, binv, vox, cnt8, res);

    k3write<<<(NTH3 + 255) / 256, 256, 0, stream>>>(res, sidx, (float*)d_out);
}

// Round 5
// 369.062 us; speedup vs baseline: 6.3871x; 1.8149x over previous
//
#include <hip/hip_runtime.h>

// ---- problem constants ----
#define BATCH 2
#define DIN 65
#define D2IN (65*65)
#define D3IN (65*65*65)
#define NTOT (2*D3IN)   // 549250
#define DO 32
#define DP 34           // padded 32 + 2 halo
#define C2 32
#define CO 100
#define CAP 8192        // per parity-class capacity
#define EPS 1e-5f

typedef __attribute__((ext_vector_type(8))) short short8;
typedef __attribute__((ext_vector_type(4))) float floatx4;

// workspace layout (float offsets)
#define H1B_OFF 0                       // bf16 [2][34][34][34][32] = 2515456 us = 1257728 f
#define H2B_OFF 1257728                 // same
#define M1_OFF  2515456                 // 65536 f
#define WB2_OFF 2580992                 // 27*2*64*8 bf16 = 13824 f
#define WB3_OFF 2594816                 // 27*7*64*8 bf16 = 48384 f
#define CNT8_OFF 2643200                // 8 ints
#define VOX_OFF 2643208                 // 65536 ints
#define SIDX_OFF 2708744                // 549250 ints
#define RES_OFF 3258000                 // 65536*112 f = 7340032
// total 10598032 floats ~= 42.4 MB

__device__ __forceinline__ unsigned short f2bf(float f) {
    unsigned int u = __float_as_uint(f);
    return (unsigned short)((u + 0x7fffu + ((u >> 16) & 1u)) >> 16);
}

// ---------------- kprep: zero h1b/h2b, prepack W2 & Winv into B-fragment layout ----------------
__global__ __launch_bounds__(256) void kprep(
    uint4* __restrict__ zp, int n4,
    const float* __restrict__ W2, const float* __restrict__ Winv,
    unsigned short* __restrict__ wb2, unsigned short* __restrict__ wb3,
    int* __restrict__ cnt8)
{
    int gid = blockIdx.x * 256 + threadIdx.x;
    int stride = gridDim.x * 256;
    uint4 zv; zv.x = 0; zv.y = 0; zv.z = 0; zv.w = 0;
    for (int i = gid; i < n4; i += stride) zp[i] = zv;

    // wb2: [tap][ct(2)][lane] -> 8 bf16 (B-frag: k=(lane>>4)*8+j, n=ct*16+(lane&15))
    for (int q = gid; q < 27 * 2 * 64; q += stride) {
        int tap = q >> 7, r = q & 127, ct = r >> 6, lane = r & 63;
        int n = ct * 16 + (lane & 15), kq = lane >> 4;
        union { unsigned short h[8]; uint4 v; } u;
#pragma unroll
        for (int j = 0; j < 8; j++) {
            int k = kq * 8 + j;
            u.h[j] = f2bf(W2[n * 864 + k * 27 + tap]);
        }
        *(uint4*)(wb2 + q * 8) = u.v;
    }
    // wb3: [tap][ct(7)][lane] -> 8 bf16; co = ct*16+(lane&15), pad co>=100 with 0
    for (int q = gid; q < 27 * 7 * 64; q += stride) {
        int tap = q / 448, r = q % 448, ct = r >> 6, lane = r & 63;
        int co = ct * 16 + (lane & 15), kq = lane >> 4;
        union { unsigned short h[8]; uint4 v; } u;
#pragma unroll
        for (int j = 0; j < 8; j++) {
            int k = kq * 8 + j;
            u.h[j] = (co < 100) ? f2bf(Winv[(co * 32 + k) * 27 + tap]) : (unsigned short)0;
        }
        *(uint4*)(wb3 + q * 8) = u.v;
    }
    if (gid < 8) cnt8[gid] = 0;
}

// ---------------- kcompact: two-sweep block-aggregated parity bucketing ----------------
__global__ __launch_bounds__(256) void kcompact(
    const int* __restrict__ mask0, int* __restrict__ sidx,
    int* __restrict__ vox, int* __restrict__ cnt8)
{
    __shared__ int lcnt[8], lbase[8];
    int tid = threadIdx.x;
    const int chunk = (NTOT + 255) / 256;
    int start = blockIdx.x * chunk;
    int end = start + chunk; if (end > NTOT) end = NTOT;
    if (tid < 8) lcnt[tid] = 0;
    __syncthreads();
    for (int t = start + tid; t < end; t += 256) {
        if (mask0[t]) {
            int r = t % D3IN;
            int z = r / D2IN; int rem = r % D2IN;
            int y = rem / DIN; int x = rem % DIN;
            atomicAdd(&lcnt[((z & 1) << 2) | ((y & 1) << 1) | (x & 1)], 1);
        }
    }
    __syncthreads();
    if (tid < 8) {
        lbase[tid] = lcnt[tid] ? atomicAdd(&cnt8[tid], lcnt[tid]) : 0;
        lcnt[tid] = 0;
    }
    __syncthreads();
    for (int t = start + tid; t < end; t += 256) {
        int s = -1;
        if (mask0[t]) {
            int bb = t / D3IN; int r = t % D3IN;
            int z = r / D2IN; int rem = r % D2IN;
            int y = rem / DIN; int x = rem % DIN;
            int cls = ((z & 1) << 2) | ((y & 1) << 1) | (x & 1);
            int loff = atomicAdd(&lcnt[cls], 1);
            int slot = lbase[cls] + loff;
            if (slot < CAP) {
                s = cls * CAP + slot;
                vox[s] = (bb << 21) | (z << 14) | (y << 7) | x;
            }
        }
        sidx[t] = s;
    }
}

// ---------------- k1: conv1 + BN + ReLU + mask -> h1 bf16 padded ----------------
__global__ __launch_bounds__(128) void k1(
    const float* __restrict__ x, const int* __restrict__ mask0,
    const float* __restrict__ W1, const float* __restrict__ b1,
    const float* __restrict__ g1, const float* __restrict__ bt1,
    const float* __restrict__ rm1, const float* __restrict__ rv1,
    unsigned short* __restrict__ h1b, float* __restrict__ m1)
{
    int t = blockIdx.x * 128 + threadIdx.x;
    int b = t >> 15, r = t & 32767;
    int z = r >> 10, y = (r >> 5) & 31, xo = r & 31;

    const float* xb = x + b * D3IN;
    const int*   mb = mask0 + b * D3IN;

    float xv[27];
    int any = 0;
#pragma unroll
    for (int kd = 0; kd < 3; kd++)
#pragma unroll
        for (int kh = 0; kh < 3; kh++)
#pragma unroll
            for (int kw = 0; kw < 3; kw++) {
                int idx = (2 * z + kd) * D2IN + (2 * y + kh) * DIN + (2 * xo + kw);
                xv[kd * 9 + kh * 3 + kw] = xb[idx];
                any |= mb[idx];
            }
    float m1f = any ? 1.0f : 0.0f;
    m1[t] = m1f;

    union { unsigned short h[32]; uint4 v[4]; } u;
#pragma unroll 4
    for (int co = 0; co < 32; co++) {
        float a = 0.f;
#pragma unroll
        for (int k = 0; k < 27; k++) a += xv[k] * W1[co * 27 + k];
        float s = g1[co] * rsqrtf(rv1[co] + EPS);
        float v = (a + b1[co] - rm1[co]) * s + bt1[co];
        u.h[co] = f2bf(fmaxf(v, 0.f) * m1f);
    }
    uint4* out4 = (uint4*)(h1b + (size_t)((((b * DP + z + 1) * DP + (y + 1)) * DP + (xo + 1)) * C2));
#pragma unroll
    for (int q = 0; q < 4; q++) out4[q] = u.v[q];
}

// ---------------- k2: conv2 as MFMA gather-GEMM; h2 bf16 out ----------------
// 1024 blocks x 256; wave = one m-tile (16 consecutive voxels), N=32 (2 co-tiles), K=32x27taps
__global__ __launch_bounds__(256) void k2(
    const unsigned short* __restrict__ h1b, const unsigned short* __restrict__ wb2,
    const float* __restrict__ b2, const float* __restrict__ g2,
    const float* __restrict__ bt2, const float* __restrict__ rm2,
    const float* __restrict__ rv2, const float* __restrict__ m1,
    unsigned short* __restrict__ h2b)
{
    int tid = threadIdx.x;
    int wv = tid >> 6, lane = tid & 63;
    int mtile = blockIdx.x * 4 + wv;      // [0,4096)
    int v0 = mtile * 16;
    int b = v0 >> 15, r = v0 & 32767;
    int z = r >> 10, y = (r >> 5) & 31, x0 = r & 31;

    int m = lane & 15, kq = lane >> 4;
    // A base: h1b element offset for this lane's row+kslice (tap offset added in loop)
    const unsigned short* abase = h1b +
        (size_t)((((b * DP + z) * DP + y) * DP + x0 + m) * C2 + kq * 8);

    floatx4 acc[2];
    acc[0] = (floatx4){0.f, 0.f, 0.f, 0.f};
    acc[1] = (floatx4){0.f, 0.f, 0.f, 0.f};

    for (int kd = 0; kd < 3; kd++)
#pragma unroll
        for (int kh = 0; kh < 3; kh++)
#pragma unroll
            for (int kw = 0; kw < 3; kw++) {
                int tap = (kd * 3 + kh) * 3 + kw;
                short8 a = *(const short8*)(abase + ((kd * DP + kh) * DP + kw) * C2);
                short8 w0 = *(const short8*)(wb2 + ((tap * 2 + 0) * 64 + lane) * 8);
                short8 w1 = *(const short8*)(wb2 + ((tap * 2 + 1) * 64 + lane) * 8);
                acc[0] = __builtin_amdgcn_mfma_f32_16x16x32_bf16(a, w0, acc[0], 0, 0, 0);
                acc[1] = __builtin_amdgcn_mfma_f32_16x16x32_bf16(a, w1, acc[1], 0, 0, 0);
            }

    // epilogue: BN+ReLU+mask, store bf16 to padded h2
    float mf[4];
#pragma unroll
    for (int i = 0; i < 4; i++) mf[i] = m1[v0 + kq * 4 + i];
#pragma unroll
    for (int ct = 0; ct < 2; ct++) {
        int co = ct * 16 + m;
        float s = g2[co] * rsqrtf(rv2[co] + EPS);
        float sh = (b2[co] - rm2[co]) * s + bt2[co];
#pragma unroll
        for (int i = 0; i < 4; i++) {
            int row = kq * 4 + i;
            float val = fmaxf(acc[ct][i] * s + sh, 0.f) * mf[i];
            h2b[(size_t)((((b * DP + z + 1) * DP + (y + 1)) * DP + (x0 + row + 1)) * C2 + co)]
                = f2bf(val);
        }
    }
}

// ---------------- k3compute: inverse conv as MFMA gather-GEMM over parity classes ----------------
// grid (64, 8) x 256; wave = one m-tile of 16 class voxels; N=112 (7 co-tiles)
__global__ __launch_bounds__(256) void k3compute(
    const unsigned short* __restrict__ h2b, const unsigned short* __restrict__ wb3,
    const float* __restrict__ binv, const int* __restrict__ vox,
    const int* __restrict__ cnt8, float* __restrict__ res)
{
    int cls = blockIdx.y;
    int pd = (cls >> 2) & 1, ph = (cls >> 1) & 1, pw = cls & 1;
    int nh = 2 - ph, nw = 2 - pw, nhw = nh * nw;
    int ntap = (2 - pd) * nhw;
    int tid = threadIdx.x;
    int wv = tid >> 6, lane = tid & 63;
    int m = lane & 15, kq = lane >> 4;

    int n = cnt8[cls]; if (n > CAP) n = CAP;
    int ntiles = (n + 15) >> 4;

    float bv[7];
#pragma unroll
    for (int ct = 0; ct < 7; ct++) {
        int co = ct * 16 + m;
        bv[ct] = (co < 100) ? binv[co] : 0.f;
    }

    for (int t = blockIdx.x * 4 + wv; t < ntiles; t += 64 * 4) {
        int idx = t * 16 + m; if (idx >= n) idx = n - 1;
        unsigned int pv = (unsigned int)vox[cls * CAP + idx];
        int xx = pv & 127, yy = (pv >> 7) & 127, zz = (pv >> 14) & 127, bb = (pv >> 21) & 1;
        const unsigned short* abase = h2b +
            (size_t)(((((bb * DP + (zz >> 1) + pd) * DP + (yy >> 1) + ph) * DP
                       + (xx >> 1) + pw)) * C2 + kq * 8);

        floatx4 acc[7];
#pragma unroll
        for (int ct = 0; ct < 7; ct++) acc[ct] = (floatx4){0.f, 0.f, 0.f, 0.f};

        for (int tl = 0; tl < ntap; tl++) {
            int td = tl / nhw, rr = tl % nhw, th = rr / nw, tw = rr % nw;
            int tap = (pd + 2 * td) * 9 + (ph + 2 * th) * 3 + (pw + 2 * tw);
            short8 a = *(const short8*)(abase + ((td * DP + th) * DP + tw) * C2);
#pragma unroll
            for (int ct = 0; ct < 7; ct++) {
                short8 w = *(const short8*)(wb3 + ((tap * 7 + ct) * 64 + lane) * 8);
                acc[ct] = __builtin_amdgcn_mfma_f32_16x16x32_bf16(a, w, acc[ct], 0, 0, 0);
            }
        }
        // store: row = kq*4+i (slot), col = ct*16+m (co); res row stride 112
#pragma unroll
        for (int ct = 0; ct < 7; ct++) {
            int co = ct * 16 + m;
#pragma unroll
            for (int i = 0; i < 4; i++) {
                int ridx = t * 16 + kq * 4 + i;
                if (ridx < n)
                    res[(size_t)(cls * CAP + ridx) * 112 + co] = acc[ct][i] + bv[ct];
            }
        }
    }
}

// ---------------- k3write: row-per-block dense writer (zero-fill + scatter fused) ----------------
// grid = 2*65*65 rows x 256 (4 waves x 64 lanes); wave = co-quarter, lane = x
__global__ __launch_bounds__(256) void k3write(
    const float* __restrict__ res, const int* __restrict__ sidx,
    float* __restrict__ out)
{
    __shared__ int ls[65];
    int blk = blockIdx.x;                  // b*4225 + z*65 + y
    int y = blk % 65; int t2 = blk / 65;
    int z = t2 % 65;  int b = t2 / 65;
    int tid = threadIdx.x;
    int roff = b * D3IN + z * D2IN + y * DIN;
    if (tid < 65) ls[tid] = sidx[roff + tid];
    __syncthreads();

    int wv = tid >> 6, lane = tid & 63;
    int s = ls[lane];
    int s64 = ls[64];
    float* obase = out + (size_t)b * 100 * D3IN + z * D2IN + y * DIN;

#pragma unroll 5
    for (int j = 0; j < 25; j++) {
        int co = wv * 25 + j;
        float val = (s >= 0) ? res[(size_t)s * 112 + co] : 0.f;
        float* orow = obase + (size_t)co * D3IN;
        orow[lane] = val;
        if (lane == 0)
            orow[64] = (s64 >= 0) ? res[(size_t)s64 * 112 + co] : 0.f;
    }
}

extern "C" void kernel_launch(void* const* d_in, const int* in_sizes, int n_in,
                              void* d_out, int out_size, void* d_ws, size_t ws_size,
                              hipStream_t stream) {
    const float* x    = (const float*)d_in[0];
    const int*  mask0 = (const int*)  d_in[1];
    const float* W1   = (const float*)d_in[2];
    const float* b1   = (const float*)d_in[3];
    const float* g1   = (const float*)d_in[4];
    const float* bt1  = (const float*)d_in[5];
    const float* rm1  = (const float*)d_in[6];
    const float* rv1  = (const float*)d_in[7];
    const float* W2   = (const float*)d_in[8];
    const float* b2   = (const float*)d_in[9];
    const float* g2   = (const float*)d_in[10];
    const float* bt2  = (const float*)d_in[11];
    const float* rm2  = (const float*)d_in[12];
    const float* rv2  = (const float*)d_in[13];
    const float* Winv = (const float*)d_in[14];
    const float* binv = (const float*)d_in[15];

    float* ws = (float*)d_ws;
    unsigned short* h1b = (unsigned short*)(ws + H1B_OFF);
    unsigned short* h2b = (unsigned short*)(ws + H2B_OFF);
    float* m1   = ws + M1_OFF;
    unsigned short* wb2 = (unsigned short*)(ws + WB2_OFF);
    unsigned short* wb3 = (unsigned short*)(ws + WB3_OFF);
    int*   cnt8 = (int*)(ws + CNT8_OFF);
    int*   vox  = (int*)(ws + VOX_OFF);
    int*   sidx = (int*)(ws + SIDX_OFF);
    float* res  = ws + RES_OFF;

    // zero h1b + h2b (adjacent bf16 regions): 2*2515456 ushorts = 628864 uint4
    int n4 = (2 * 2515456) / 8;
    kprep<<<1024, 256, 0, stream>>>((uint4*)ws, n4, W2, Winv, wb2, wb3, cnt8);

    kcompact<<<256, 256, 0, stream>>>(mask0, sidx, vox, cnt8);

    k1<<<512, 128, 0, stream>>>(x, mask0, W1, b1, g1, bt1, rm1, rv1, h1b, m1);

    k2<<<1024, 256, 0, stream>>>(h1b, wb2, b2, g2, bt2, rm2, rv2, m1, h2b);

    k3compute<<<dim3(64, 8), 256, 0, stream>>>(h2b, wb3, binv, vox, cnt8, res);

    k3write<<<2 * 65 * 65, 256, 0, stream>>>(res, sidx, (float*)d_out);
}

// Round 6
// 356.977 us; speedup vs baseline: 6.6033x; 1.0339x over previous
//
#include <hip/hip_runtime.h>

// ---- problem constants ----
#define BATCH 2
#define DIN 65
#define D2IN (65*65)
#define D3IN (65*65*65)
#define NTOT (2*D3IN)   // 549250
#define DO 32
#define DP 34           // padded 32 + 2 halo
#define C2 32
#define CO 100
#define CAP 8192        // per parity-class capacity
#define EPS 1e-5f

typedef __attribute__((ext_vector_type(8))) short short8;
typedef __attribute__((ext_vector_type(4))) float floatx4;

// workspace layout (float offsets)
#define H1B_OFF 0                       // bf16 [2][34][34][34][32] -> 1257728 f
#define H2B_OFF 1257728
#define M1_OFF  2515456                 // 65536 f
#define WB2_OFF 2580992                 // 27*2*64*8 bf16 = 13824 f
#define WB3_OFF 2594816                 // 27*7*64*8 bf16 = 48384 f
#define CNT8_OFF (2643200)              // 8 ints (16B-aligned)
#define VOX_OFF 2643208                 // 65536 ints
#define SIDX_OFF 2708744                // 549250 ints
#define RES_OFF 3258000                 // 16B-aligned; 65536*112 f
// total 10598032 floats ~= 42.4 MB

__device__ __forceinline__ unsigned short f2bf(float f) {
    unsigned int u = __float_as_uint(f);
    return (unsigned short)((u + 0x7fffu + ((u >> 16) & 1u)) >> 16);
}

// ================= F1: fused compact | k1 | shell-zero | weight-pack =================
// blocks [0,256): parity compact; [256,512): conv1; [512,820): halo shell zero;
// [820,881): W2/Winv B-fragment packing. All parts write-disjoint.
__global__ __launch_bounds__(256) void f1(
    const float* __restrict__ x, const int* __restrict__ mask0,
    const float* __restrict__ W1, const float* __restrict__ b1,
    const float* __restrict__ g1, const float* __restrict__ bt1,
    const float* __restrict__ rm1, const float* __restrict__ rv1,
    const float* __restrict__ W2, const float* __restrict__ Winv,
    unsigned short* __restrict__ h1b, unsigned short* __restrict__ h2b,
    float* __restrict__ m1,
    unsigned short* __restrict__ wb2, unsigned short* __restrict__ wb3,
    int* __restrict__ sidx, int* __restrict__ vox, int* __restrict__ cnt8)
{
    __shared__ int lcnt[8], lbase[8];
    int bid = blockIdx.x, tid = threadIdx.x;

    if (bid < 256) {
        // ---- parity-class compaction (cnt8 pre-zeroed by hipMemsetAsync) ----
        const int chunk = (NTOT + 255) / 256;
        int start = bid * chunk;
        int end = start + chunk; if (end > NTOT) end = NTOT;
        if (tid < 8) lcnt[tid] = 0;
        __syncthreads();
        for (int t = start + tid; t < end; t += 256) {
            if (mask0[t]) {
                int r = t % D3IN;
                int z = r / D2IN; int rem = r % D2IN;
                int y = rem / DIN; int xx = rem % DIN;
                atomicAdd(&lcnt[((z & 1) << 2) | ((y & 1) << 1) | (xx & 1)], 1);
            }
        }
        __syncthreads();
        if (tid < 8) {
            lbase[tid] = lcnt[tid] ? atomicAdd(&cnt8[tid], lcnt[tid]) : 0;
            lcnt[tid] = 0;
        }
        __syncthreads();
        for (int t = start + tid; t < end; t += 256) {
            int s = -1;
            if (mask0[t]) {
                int bb = t / D3IN; int r = t % D3IN;
                int z = r / D2IN; int rem = r % D2IN;
                int y = rem / DIN; int xx = rem % DIN;
                int cls = ((z & 1) << 2) | ((y & 1) << 1) | (xx & 1);
                int loff = atomicAdd(&lcnt[cls], 1);
                int slot = lbase[cls] + loff;
                if (slot < CAP) {
                    s = cls * CAP + slot;
                    vox[s] = (bb << 21) | (z << 14) | (y << 7) | xx;
                }
            }
            sidx[t] = s;
        }
    } else if (bid < 512) {
        // ---- conv1(1->32,s2) + BN + ReLU + mask -> h1 bf16 (interior) ----
        int t = (bid - 256) * 256 + tid;   // 65536 voxels exactly
        int b = t >> 15, r = t & 32767;
        int z = r >> 10, y = (r >> 5) & 31, xo = r & 31;

        const float* xb = x + b * D3IN;
        const int*   mb = mask0 + b * D3IN;

        float xv[27];
        int any = 0;
#pragma unroll
        for (int kd = 0; kd < 3; kd++)
#pragma unroll
            for (int kh = 0; kh < 3; kh++)
#pragma unroll
                for (int kw = 0; kw < 3; kw++) {
                    int idx = (2 * z + kd) * D2IN + (2 * y + kh) * DIN + (2 * xo + kw);
                    xv[kd * 9 + kh * 3 + kw] = xb[idx];
                    any |= mb[idx];
                }
        float m1f = any ? 1.0f : 0.0f;
        m1[t] = m1f;

        union { unsigned short h[32]; uint4 v[4]; } u;
#pragma unroll 4
        for (int co = 0; co < 32; co++) {
            float a = 0.f;
#pragma unroll
            for (int k = 0; k < 27; k++) a += xv[k] * W1[co * 27 + k];
            float s = g1[co] * rsqrtf(rv1[co] + EPS);
            float v = (a + b1[co] - rm1[co]) * s + bt1[co];
            u.h[co] = f2bf(fmaxf(v, 0.f) * m1f);
        }
        uint4* out4 = (uint4*)(h1b + (size_t)((((b * DP + z + 1) * DP + (y + 1)) * DP + (xo + 1)) * C2));
#pragma unroll
        for (int q = 0; q < 4; q++) out4[q] = u.v[q];
    } else if (bid < 820) {
        // ---- halo shell zero for h1b and h2b ----
        int gid = (bid - 512) * 256 + tid;
        if (gid < 2 * 39304) {
            int b = gid / 39304; int r = gid % 39304;
            int z = r / 1156; int rem = r % 1156;
            int y = rem / 34; int xx = rem % 34;
            if (z == 0 || z == 33 || y == 0 || y == 33 || xx == 0 || xx == 33) {
                size_t off = (size_t)((((b * DP + z) * DP + y) * DP + xx) * C2);
                uint4 zv; zv.x = 0; zv.y = 0; zv.z = 0; zv.w = 0;
                uint4* p1 = (uint4*)(h1b + off);
                uint4* p2 = (uint4*)(h2b + off);
#pragma unroll
                for (int q = 0; q < 4; q++) { p1[q] = zv; p2[q] = zv; }
            }
        }
    } else {
        // ---- pack W2 / Winv into MFMA B-fragment layout ----
        int gid = (bid - 820) * 256 + tid;
        if (gid < 27 * 2 * 64) {
            int q = gid;
            int tap = q >> 7, r = q & 127, ct = r >> 6, lane = r & 63;
            int n = ct * 16 + (lane & 15), kq = lane >> 4;
            union { unsigned short h[8]; uint4 v; } u;
#pragma unroll
            for (int j = 0; j < 8; j++) {
                int k = kq * 8 + j;
                u.h[j] = f2bf(W2[n * 864 + k * 27 + tap]);
            }
            *(uint4*)(wb2 + q * 8) = u.v;
        } else if (gid < 27 * 2 * 64 + 27 * 7 * 64) {
            int q = gid - 27 * 2 * 64;
            int tap = q / 448, r = q % 448, ct = r >> 6, lane = r & 63;
            int co = ct * 16 + (lane & 15), kq = lane >> 4;
            union { unsigned short h[8]; uint4 v; } u;
#pragma unroll
            for (int j = 0; j < 8; j++) {
                int k = kq * 8 + j;
                u.h[j] = (co < 100) ? f2bf(Winv[(co * 32 + k) * 27 + tap]) : (unsigned short)0;
            }
            *(uint4*)(wb3 + q * 8) = u.v;
        }
    }
}

// ---------------- k2: conv2 as MFMA gather-GEMM; h2 bf16 out ----------------
__global__ __launch_bounds__(256) void k2(
    const unsigned short* __restrict__ h1b, const unsigned short* __restrict__ wb2,
    const float* __restrict__ b2, const float* __restrict__ g2,
    const float* __restrict__ bt2, const float* __restrict__ rm2,
    const float* __restrict__ rv2, const float* __restrict__ m1,
    unsigned short* __restrict__ h2b)
{
    int tid = threadIdx.x;
    int wv = tid >> 6, lane = tid & 63;
    int mtile = blockIdx.x * 4 + wv;      // [0,4096)
    int v0 = mtile * 16;
    int b = v0 >> 15, r = v0 & 32767;
    int z = r >> 10, y = (r >> 5) & 31, x0 = r & 31;

    int m = lane & 15, kq = lane >> 4;
    const unsigned short* abase = h1b +
        (size_t)((((b * DP + z) * DP + y) * DP + x0 + m) * C2 + kq * 8);

    floatx4 acc[2];
    acc[0] = (floatx4){0.f, 0.f, 0.f, 0.f};
    acc[1] = (floatx4){0.f, 0.f, 0.f, 0.f};

    for (int kd = 0; kd < 3; kd++)
#pragma unroll
        for (int kh = 0; kh < 3; kh++)
#pragma unroll
            for (int kw = 0; kw < 3; kw++) {
                int tap = (kd * 3 + kh) * 3 + kw;
                short8 a = *(const short8*)(abase + ((kd * DP + kh) * DP + kw) * C2);
                short8 w0 = *(const short8*)(wb2 + ((tap * 2 + 0) * 64 + lane) * 8);
                short8 w1 = *(const short8*)(wb2 + ((tap * 2 + 1) * 64 + lane) * 8);
                acc[0] = __builtin_amdgcn_mfma_f32_16x16x32_bf16(a, w0, acc[0], 0, 0, 0);
                acc[1] = __builtin_amdgcn_mfma_f32_16x16x32_bf16(a, w1, acc[1], 0, 0, 0);
            }

    float mf[4];
#pragma unroll
    for (int i = 0; i < 4; i++) mf[i] = m1[v0 + kq * 4 + i];
#pragma unroll
    for (int ct = 0; ct < 2; ct++) {
        int co = ct * 16 + m;
        float s = g2[co] * rsqrtf(rv2[co] + EPS);
        float sh = (b2[co] - rm2[co]) * s + bt2[co];
#pragma unroll
        for (int i = 0; i < 4; i++) {
            int row = kq * 4 + i;
            float val = fmaxf(acc[ct][i] * s + sh, 0.f) * mf[i];
            h2b[(size_t)((((b * DP + z + 1) * DP + (y + 1)) * DP + (x0 + row + 1)) * C2 + co)]
                = f2bf(val);
        }
    }
}

// ---------------- k3compute: inverse conv as MFMA gather-GEMM; res stride 112 ----------------
__global__ __launch_bounds__(256) void k3compute(
    const unsigned short* __restrict__ h2b, const unsigned short* __restrict__ wb3,
    const float* __restrict__ binv, const int* __restrict__ vox,
    const int* __restrict__ cnt8, float* __restrict__ res)
{
    int cls = blockIdx.y;
    int pd = (cls >> 2) & 1, ph = (cls >> 1) & 1, pw = cls & 1;
    int nh = 2 - ph, nw = 2 - pw, nhw = nh * nw;
    int ntap = (2 - pd) * nhw;
    int tid = threadIdx.x;
    int wv = tid >> 6, lane = tid & 63;
    int m = lane & 15, kq = lane >> 4;

    int n = cnt8[cls]; if (n > CAP) n = CAP;
    int ntiles = (n + 15) >> 4;

    float bv[7];
#pragma unroll
    for (int ct = 0; ct < 7; ct++) {
        int co = ct * 16 + m;
        bv[ct] = (co < 100) ? binv[co] : 0.f;
    }

    for (int t = blockIdx.x * 4 + wv; t < ntiles; t += 64 * 4) {
        int idx = t * 16 + m; if (idx >= n) idx = n - 1;
        unsigned int pv = (unsigned int)vox[cls * CAP + idx];
        int xx = pv & 127, yy = (pv >> 7) & 127, zz = (pv >> 14) & 127, bb = (pv >> 21) & 1;
        const unsigned short* abase = h2b +
            (size_t)(((((bb * DP + (zz >> 1) + pd) * DP + (yy >> 1) + ph) * DP
                       + (xx >> 1) + pw)) * C2 + kq * 8);

        floatx4 acc[7];
#pragma unroll
        for (int ct = 0; ct < 7; ct++) acc[ct] = (floatx4){0.f, 0.f, 0.f, 0.f};

        for (int tl = 0; tl < ntap; tl++) {
            int td = tl / nhw, rr = tl % nhw, th = rr / nw, tw = rr % nw;
            int tap = (pd + 2 * td) * 9 + (ph + 2 * th) * 3 + (pw + 2 * tw);
            short8 a = *(const short8*)(abase + ((td * DP + th) * DP + tw) * C2);
#pragma unroll
            for (int ct = 0; ct < 7; ct++) {
                short8 w = *(const short8*)(wb3 + ((tap * 7 + ct) * 64 + lane) * 8);
                acc[ct] = __builtin_amdgcn_mfma_f32_16x16x32_bf16(a, w, acc[ct], 0, 0, 0);
            }
        }
#pragma unroll
        for (int ct = 0; ct < 7; ct++) {
            int co = ct * 16 + m;
#pragma unroll
            for (int i = 0; i < 4; i++) {
                int ridx = t * 16 + kq * 4 + i;
                if (ridx < n)
                    res[(size_t)(cls * CAP + ridx) * 112 + co] = acc[ct][i] + bv[ct];
            }
        }
    }
}

// ---------------- k3write v3: batched reads, coalesced dense writer ----------------
// block = (b,z,y) row; wave wv covers co in [wv*28, wv*28+28) ∩ [0,100); lane = x
__global__ __launch_bounds__(256) void k3write(
    const float* __restrict__ res, const int* __restrict__ sidx,
    float* __restrict__ out)
{
    __shared__ int ls[65];
    int blk = blockIdx.x;                  // b*4225 + z*65 + y
    int y = blk % 65; int t2 = blk / 65;
    int z = t2 % 65;  int b = t2 / 65;
    int tid = threadIdx.x;
    int roff = b * D3IN + z * D2IN + y * DIN;
    if (tid < 65) ls[tid] = sidx[roff + tid];
    __syncthreads();

    int wv = tid >> 6, lane = tid & 63;
    int s = ls[lane];
    int s64 = ls[64];

    union { float4 q[7]; float f[28]; } u;
    if (s >= 0) {
        const float4* rp = (const float4*)(res + (size_t)s * 112 + wv * 28);
#pragma unroll
        for (int j = 0; j < 7; j++) u.q[j] = rp[j];
    } else {
#pragma unroll
        for (int j = 0; j < 7; j++) u.q[j] = make_float4(0.f, 0.f, 0.f, 0.f);
    }
    union { float4 q[7]; float f[28]; } u64;
    if (lane == 0) {
        if (s64 >= 0) {
            const float4* rp = (const float4*)(res + (size_t)s64 * 112 + wv * 28);
#pragma unroll
            for (int j = 0; j < 7; j++) u64.q[j] = rp[j];
        } else {
#pragma unroll
            for (int j = 0; j < 7; j++) u64.q[j] = make_float4(0.f, 0.f, 0.f, 0.f);
        }
    }

    float* obase = out + (size_t)b * 100 * D3IN + z * D2IN + y * DIN;
#pragma unroll
    for (int j = 0; j < 28; j++) {
        int co = wv * 28 + j;
        if (co < 100) {
            float* orow = obase + (size_t)co * D3IN;
            orow[lane] = u.f[j];
            if (lane == 0) orow[64] = u64.f[j];
        }
    }
}

extern "C" void kernel_launch(void* const* d_in, const int* in_sizes, int n_in,
                              void* d_out, int out_size, void* d_ws, size_t ws_size,
                              hipStream_t stream) {
    const float* x    = (const float*)d_in[0];
    const int*  mask0 = (const int*)  d_in[1];
    const float* W1   = (const float*)d_in[2];
    const float* b1   = (const float*)d_in[3];
    const float* g1   = (const float*)d_in[4];
    const float* bt1  = (const float*)d_in[5];
    const float* rm1  = (const float*)d_in[6];
    const float* rv1  = (const float*)d_in[7];
    const float* W2   = (const float*)d_in[8];
    const float* b2   = (const float*)d_in[9];
    const float* g2   = (const float*)d_in[10];
    const float* bt2  = (const float*)d_in[11];
    const float* rm2  = (const float*)d_in[12];
    const float* rv2  = (const float*)d_in[13];
    const float* Winv = (const float*)d_in[14];
    const float* binv = (const float*)d_in[15];

    float* ws = (float*)d_ws;
    unsigned short* h1b = (unsigned short*)(ws + H1B_OFF);
    unsigned short* h2b = (unsigned short*)(ws + H2B_OFF);
    float* m1   = ws + M1_OFF;
    unsigned short* wb2 = (unsigned short*)(ws + WB2_OFF);
    unsigned short* wb3 = (unsigned short*)(ws + WB3_OFF);
    int*   cnt8 = (int*)(ws + CNT8_OFF);
    int*   vox  = (int*)(ws + VOX_OFF);
    int*   sidx = (int*)(ws + SIDX_OFF);
    float* res  = ws + RES_OFF;

    hipMemsetAsync(cnt8, 0, 8 * sizeof(int), stream);

    f1<<<881, 256, 0, stream>>>(x, mask0, W1, b1, g1, bt1, rm1, rv1, W2, Winv,
                                h1b, h2b, m1, wb2, wb3, sidx, vox, cnt8);

    k2<<<1024, 256, 0, stream>>>(h1b, wb2, b2, g2, bt2, rm2, rv2, m1, h2b);

    k3compute<<<dim3(64, 8), 256, 0, stream>>>(h2b, wb3, binv, vox, cnt8, res);

    k3write<<<2 * 65 * 65, 256, 0, stream>>>(res, sidx, (float*)d_out);
}